// Round 3
// baseline (431.489 us; speedup 1.0000x reference)
//
#include <hip/hip_runtime.h>

#define TDIM 256
#define THEADS 8
#define TB 32
#define TN 8192
#define NPAIR (TN/2)                    // 4096
#define BLK_PER_B 16
#define WAVES_PB 4
#define GW_PER_B (BLK_PER_B*WAVES_PB)   // 64 waves per batch
#define ITERS (NPAIR/GW_PER_B)          // 64 token-pairs per wave
#define ACC_PER_B 2312                  // Y 8*256 + E 8 + S 256
#define PPAD 2368                       // padded partial stride (floats)

#if __has_builtin(__builtin_amdgcn_exp2f)
#define EXP2(x) __builtin_amdgcn_exp2f(x)
#else
#define EXP2(x) exp2f(x)
#endif

__device__ __forceinline__ float xr(float v, int m) { return v + __shfl_xor(v, m, 64); }

// butterfly stage via DPP (pure VALU, no DS pipe)
template<int CTRL>
__device__ __forceinline__ float dppadd(float v) {
  int t = __builtin_amdgcn_update_dpp(0, __float_as_int(v), CTRL, 0xF, 0xF, true);
  return v + __int_as_float(t);
}
// xor16 within each 32-lane group via ds_swizzle bit-mode
__device__ __forceinline__ float swzadd16(float v) {
  int t = __builtin_amdgcn_ds_swizzle(__float_as_int(v), 0x401F); // (16<<10)|0x1F
  return v + __int_as_float(t);
}
// full 32-lane sum (per half-wave), result on every lane of the half
__device__ __forceinline__ float red32(float v) {
  v = dppadd<0xB1>(v);   // quad_perm [1,0,3,2] = xor1
  v = dppadd<0x4E>(v);   // quad_perm [2,3,0,1] = xor2
  v = dppadd<0x141>(v);  // row_half_mirror     = xor7
  v = dppadd<0x128>(v);  // row_ror:8           = xor8 (within 16)
  return swzadd16(v);    // xor16 (within 32)
}

// prep: q = ct@Wq+bq ; w1[b,g,c] = log2e/sqrt(32) * sum_h Wt1[h,g] * (Wkv_k[c, 32h+d]·q[b,32h+d])
__global__ void tmca_prep(const float* __restrict__ ct, const float* __restrict__ Wq,
                          const float* __restrict__ bq, const float* __restrict__ Wkv,
                          const float* __restrict__ Wt1, float* __restrict__ w1) {
  int b = blockIdx.x, t = threadIdx.x;
  __shared__ float sct[TDIM], sq[TDIM], st1[64];
  sct[t] = ct[b * TDIM + t];
  if (t < 64) st1[t] = Wt1[t];
  __syncthreads();
  float a = bq[t];
  for (int c = 0; c < TDIM; ++c) a = fmaf(sct[c], Wq[c * TDIM + t], a);
  sq[t] = a;
  __syncthreads();
  float ph[THEADS];
  #pragma unroll
  for (int h = 0; h < THEADS; ++h) {
    float s = 0.f;
    #pragma unroll 8
    for (int d = 0; d < 32; ++d) s = fmaf(Wkv[t * 512 + h * 32 + d], sq[h * 32 + d], s);
    ph[h] = s;
  }
  const float sc = 0.17677669529663687f * 1.4426950408889634f;  // 1/sqrt(32) * log2(e)
  #pragma unroll
  for (int g = 0; g < THEADS; ++g) {
    float s = 0.f;
    #pragma unroll
    for (int h = 0; h < THEADS; ++h) s = fmaf(ph[h], st1[h * THEADS + g], s);
    w1[(b * THEADS + g) * TDIM + t] = s * sc;
  }
}

// streaming pass: per (b,g): E = sum_n m*2^s2', Y[c] = sum_n m*2^s2'*X[n,c], S[c] = sum_n X[n,c]
__global__ __launch_bounds__(256, 2) void tmca_main(
    const float* __restrict__ X, const int* __restrict__ mask,
    const float* __restrict__ w1, float* __restrict__ partial) {
  const int b = blockIdx.y, bk = blockIdx.x, tid = threadIdx.x;
  const int wv = tid >> 6, lane = tid & 63, half = lane >> 5, j = lane & 31;
  const int gw = bk * WAVES_PB + wv;

  const float4* w1b = (const float4*)(w1 + (size_t)b * THEADS * TDIM);
  float4 wg0[8], wg1[8];
  #pragma unroll
  for (int g = 0; g < 8; ++g) { wg0[g] = w1b[g * 64 + j]; wg1[g] = w1b[g * 64 + 32 + j]; }

  float4 Y0[8], Y1[8];
  float E[8];
  float4 S0 = make_float4(0, 0, 0, 0), S1 = make_float4(0, 0, 0, 0);
  #pragma unroll
  for (int g = 0; g < 8; ++g) {
    Y0[g] = make_float4(0, 0, 0, 0);
    Y1[g] = make_float4(0, 0, 0, 0);
    E[g] = 0.f;
  }

  const float4* Xb = (const float4*)(X + (size_t)b * TN * TDIM);
  const int* mb = mask + b * TN;
  const int n0 = 2 * gw + half;  // token for iter 0; step 128 tokens per iter

  // 2-deep prefetch, ping-pong A/B with compile-time indices
  float4 A0 = Xb[(size_t)n0 * 64 + j], A1 = Xb[(size_t)n0 * 64 + 32 + j];
  int mA = mb[n0];
  float4 B0 = Xb[(size_t)(n0 + 128) * 64 + j], B1 = Xb[(size_t)(n0 + 128) * 64 + 32 + j];
  int mB = mb[n0 + 128];

  auto body = [&](float4 x0, float4 x1, int mk) {
    float fm = (float)mk;
    float pg[8];
    #pragma unroll
    for (int g = 0; g < 8; ++g)
      pg[g] = x0.x * wg0[g].x + x0.y * wg0[g].y + x0.z * wg0[g].z + x0.w * wg0[g].w
            + x1.x * wg1[g].x + x1.y * wg1[g].y + x1.z * wg1[g].z + x1.w * wg1[g].w;
    #pragma unroll
    for (int g = 0; g < 8; ++g) pg[g] = red32(pg[g]);
    #pragma unroll
    for (int g = 0; g < 8; ++g) {
      float e = EXP2(pg[g]) * fm;
      E[g] += e;
      Y0[g].x = fmaf(e, x0.x, Y0[g].x);
      Y0[g].y = fmaf(e, x0.y, Y0[g].y);
      Y0[g].z = fmaf(e, x0.z, Y0[g].z);
      Y0[g].w = fmaf(e, x0.w, Y0[g].w);
      Y1[g].x = fmaf(e, x1.x, Y1[g].x);
      Y1[g].y = fmaf(e, x1.y, Y1[g].y);
      Y1[g].z = fmaf(e, x1.z, Y1[g].z);
      Y1[g].w = fmaf(e, x1.w, Y1[g].w);
    }
    S0.x += x0.x; S0.y += x0.y; S0.z += x0.z; S0.w += x0.w;
    S1.x += x1.x; S1.y += x1.y; S1.z += x1.z; S1.w += x1.w;
  };

  for (int it = 0; it < ITERS - 2; it += 2) {
    {
      float4 x0 = A0, x1 = A1; int mk = mA;
      int nn = n0 + 128 * (it + 2);
      A0 = Xb[(size_t)nn * 64 + j]; A1 = Xb[(size_t)nn * 64 + 32 + j]; mA = mb[nn];
      body(x0, x1, mk);
    }
    {
      float4 x0 = B0, x1 = B1; int mk = mB;
      int nn = n0 + 128 * (it + 3);
      B0 = Xb[(size_t)nn * 64 + j]; B1 = Xb[(size_t)nn * 64 + 32 + j]; mB = mb[nn];
      body(x0, x1, mk);
    }
  }
  body(A0, A1, mA);
  body(B0, B1, mB);

  // combine the two token-halves of the wave (once per kernel; ds_bpermute ok here)
  #pragma unroll
  for (int g = 0; g < 8; ++g) {
    Y0[g].x = xr(Y0[g].x, 32); Y0[g].y = xr(Y0[g].y, 32);
    Y0[g].z = xr(Y0[g].z, 32); Y0[g].w = xr(Y0[g].w, 32);
    Y1[g].x = xr(Y1[g].x, 32); Y1[g].y = xr(Y1[g].y, 32);
    Y1[g].z = xr(Y1[g].z, 32); Y1[g].w = xr(Y1[g].w, 32);
    E[g] = xr(E[g], 32);
  }
  S0.x = xr(S0.x, 32); S0.y = xr(S0.y, 32); S0.z = xr(S0.z, 32); S0.w = xr(S0.w, 32);
  S1.x = xr(S1.x, 32); S1.y = xr(S1.y, 32); S1.z = xr(S1.z, 32); S1.w = xr(S1.w, 32);

  // block reduction in LDS, one coalesced partial write per block (no atomics)
  __shared__ float red[WAVES_PB][ACC_PER_B];
  float* sl = red[wv];
  if (lane < 32) {
    #pragma unroll
    for (int g = 0; g < 8; ++g) {
      ((float4*)(sl + g * TDIM))[j] = Y0[g];
      ((float4*)(sl + g * TDIM + 128))[j] = Y1[g];
    }
    ((float4*)(sl + 2056))[j] = S0;
    ((float4*)(sl + 2056 + 128))[j] = S1;
    if (lane == 0) {
      #pragma unroll
      for (int g = 0; g < 8; ++g) sl[2048 + g] = E[g];
    }
  }
  __syncthreads();
  float* pb = partial + (size_t)(b * BLK_PER_B + bk) * PPAD;
  for (int idx = tid; idx < ACC_PER_B; idx += 256)
    pb[idx] = red[0][idx] + red[1][idx] + red[2][idx] + red[3][idx];
}

// finalize: reduce partials, z = Wt2^T·(Y/E) + bt2*S, out_pre = z·Wkv_v + T*bkv_v, out = out_pre@Wout+bout
__global__ void tmca_fin(const float* __restrict__ partial, const float* __restrict__ Wkv,
                         const float* __restrict__ bkv, const float* __restrict__ Wt2,
                         const float* __restrict__ bt2, const float* __restrict__ Wout,
                         const float* __restrict__ bout, float* __restrict__ out) {
  int b = blockIdx.x, t = threadIdx.x;
  __shared__ float sacc[ACC_PER_B];
  __shared__ float z[THEADS][TDIM];
  __shared__ float opre[TDIM];
  __shared__ float sWt2[64], sbt2[8];
  const float* pb = partial + (size_t)b * BLK_PER_B * PPAD;
  for (int idx = t; idx < ACC_PER_B; idx += 256) {
    float s = 0.f;
    #pragma unroll
    for (int k = 0; k < BLK_PER_B; ++k) s += pb[(size_t)k * PPAD + idx];
    sacc[idx] = s;
  }
  if (t < 64) sWt2[t] = Wt2[t];
  if (t < 8) sbt2[t] = bt2[t];
  __syncthreads();
  float Yc[THEADS];
  #pragma unroll
  for (int g = 0; g < THEADS; ++g) Yc[g] = sacc[g * TDIM + t] / sacc[2048 + g];
  float Sc = sacc[2056 + t];
  #pragma unroll
  for (int g2 = 0; g2 < THEADS; ++g2) {
    float a = 0.f;
    #pragma unroll
    for (int g = 0; g < THEADS; ++g) a = fmaf(sWt2[g * THEADS + g2], Yc[g], a);
    z[g2][t] = a + sbt2[g2] * Sc;
  }
  __syncthreads();
  {
    int g2 = t >> 5;
    float T = 0.f;
    #pragma unroll
    for (int g = 0; g < THEADS; ++g) T += sWt2[g * THEADS + g2];
    T += (float)TN * sbt2[g2];
    float a = 0.f;
    for (int c = 0; c < TDIM; ++c) a = fmaf(z[g2][c], Wkv[c * 512 + 256 + t], a);
    opre[t] = a + T * bkv[256 + t];
  }
  __syncthreads();
  float a = bout[t];
  for (int c = 0; c < TDIM; ++c) a = fmaf(opre[c], Wout[c * TDIM + t], a);
  out[b * TDIM + t] = a;
}

extern "C" void kernel_launch(void* const* d_in, const int* in_sizes, int n_in,
                              void* d_out, int out_size, void* d_ws, size_t ws_size,
                              hipStream_t stream) {
  const float* X    = (const float*)d_in[0];
  const float* ct   = (const float*)d_in[1];
  const int*   msk  = (const int*)d_in[2];
  const float* Wkv  = (const float*)d_in[3];
  const float* bkv  = (const float*)d_in[4];
  const float* Wq   = (const float*)d_in[5];
  const float* bq   = (const float*)d_in[6];
  const float* Wt1  = (const float*)d_in[7];
  // d_in[8] = b_t1: per-(b,g) constant shift -> softmax-invariant, unused
  const float* Wt2  = (const float*)d_in[9];
  const float* bt2  = (const float*)d_in[10];
  const float* Wout = (const float*)d_in[11];
  const float* bout = (const float*)d_in[12];
  float* out = (float*)d_out;

  float* ws      = (float*)d_ws;     // w1: 65536 floats; partial: 512*PPAD floats (~4.9 MB)
  float* w1      = ws;
  float* partial = ws + TB * THEADS * TDIM;

  hipLaunchKernelGGL(tmca_prep, dim3(TB), dim3(256), 0, stream, ct, Wq, bq, Wkv, Wt1, w1);
  hipLaunchKernelGGL(tmca_main, dim3(BLK_PER_B, TB), dim3(256), 0, stream, X, msk, w1, partial);
  hipLaunchKernelGGL(tmca_fin, dim3(TB), dim3(256), 0, stream, partial, Wkv, bkv, Wt2, bt2,
                     Wout, bout, out);
}